// Round 7
// baseline (306.400 us; speedup 1.0000x reference)
//
#include <hip/hip_runtime.h>
#include <hip/hip_bf16.h>

#define D_MODEL 1024
#define BB 4
#define TT 2048
#define ROWS (BB*TT)     /* 8192 */
#define NCHUNK 64
#define CHLEN 32         /* NCHUNK*CHLEN == TT */

typedef __attribute__((ext_vector_type(8))) short short8;
typedef __attribute__((ext_vector_type(4))) float floatx4;

static __device__ __forceinline__ ushort f2bf(float f) {
    union { float f; unsigned u; } v; v.f = f;
    unsigned r = v.u + 0x7FFF + ((v.u >> 16) & 1);   // RNE
    return (ushort)(r >> 16);
}
static __device__ __forceinline__ float bf2f(ushort b) {
    union { unsigned u; float f; } v; v.u = ((unsigned)b) << 16;
    return v.f;
}
static __device__ __forceinline__ float silu(float x) {
    return x / (1.f + __expf(-x));
}

// async global->LDS, 16B per lane; LDS dest is wave-uniform base + lane*16
#define GLOAD_LDS16(gp, lp)                                                 \
    __builtin_amdgcn_global_load_lds(                                       \
        (const __attribute__((address_space(1))) void*)(gp),                \
        (__attribute__((address_space(3))) void*)(lp), 16, 0, 0)

// ---------------- fused prep ----------------
#define PREP_A 8192
#define PREP_B 4096
#define PREP_C 2048
__global__ __launch_bounds__(256) void prep_all(
    const float* __restrict__ x, ushort* __restrict__ xb,
    const float* __restrict__ W_in, ushort* __restrict__ WinT,
    const float* __restrict__ W_out, ushort* __restrict__ W1T,
    const float* __restrict__ lnw, const float* __restrict__ lnb,
    float* __restrict__ s1, float* __restrict__ c2,
    const float* __restrict__ nu_log, const float* __restrict__ theta_log,
    const float* __restrict__ gamma_log,
    float* __restrict__ fr, float* __restrict__ fi, float* __restrict__ gm) {
    __shared__ float smem[32 * 33 + 8 * 32 * 2];
    int bid = blockIdx.x, tid = threadIdx.x;
    if (bid < PREP_A) {
        int i = bid * 256 + tid;
        float4 v = ((const float4*)x)[i];
        ushort4 o;
        o.x = f2bf(v.x); o.y = f2bf(v.y); o.z = f2bf(v.z); o.w = f2bf(v.w);
        ((ushort4*)xb)[i] = o;
    } else if (bid < PREP_A + PREP_B) {
        int b2 = bid - PREP_A;                  // W_in: K=1024, N=4096
        int n0 = (b2 & 127) * 32, k0 = (b2 >> 7) * 32;
        int tx = tid & 31, ty = tid >> 5;
        float (*tile)[33] = (float (*)[33])smem;
#pragma unroll
        for (int j = 0; j < 4; ++j)
            tile[ty + j*8][tx] = W_in[(size_t)(k0 + ty + j*8) * 4096 + n0 + tx];
        __syncthreads();
#pragma unroll
        for (int j = 0; j < 4; ++j)
            WinT[(size_t)(n0 + ty + j*8) * 1024 + k0 + tx] = f2bf(tile[tx][ty + j*8]);
    } else if (bid < PREP_A + PREP_B + PREP_C) {
        int b2 = bid - PREP_A - PREP_B;         // W_out: K=2048, N=1024
        int n0 = (b2 & 31) * 32, k0 = (b2 >> 5) * 32;
        int tx = tid & 31, ty = tid >> 5;
        float (*tile)[33] = (float (*)[33])smem;
        float* red1 = smem + 32 * 33;
        float* red2 = red1 + 8 * 32;
        float p1 = 0.f, p2 = 0.f;              // col sums for n = n0+tx
#pragma unroll
        for (int j = 0; j < 4; ++j) {
            int k = k0 + ty + j * 8;
            float w = W_out[(size_t)k * 1024 + n0 + tx];
            float lw = lnw[k], lb = lnb[k];
            tile[ty + j*8][tx] = lw * w;
            p1 += lw * w; p2 += lb * w;
        }
        __syncthreads();
#pragma unroll
        for (int j = 0; j < 4; ++j)
            W1T[(size_t)(n0 + ty + j*8) * 2048 + k0 + tx] = f2bf(tile[tx][ty + j*8]);
        red1[ty * 32 + tx] = p1; red2[ty * 32 + tx] = p2;
        __syncthreads();
        if (ty == 0) {
            float a = 0.f, b = 0.f;
#pragma unroll
            for (int t = 0; t < 8; ++t) { a += red1[t * 32 + tx]; b += red2[t * 32 + tx]; }
            atomicAdd(&s1[n0 + tx], a);
            atomicAdd(&c2[n0 + tx], b);
        }
    } else {
        int c = (bid - PREP_A - PREP_B - PREP_C) * 256 + tid;
        if (c < D_MODEL) {
            float nu = expf(-expf(nu_log[c]));
            float th = expf(theta_log[c]);
            fr[c] = nu * cosf(th);
            fi[c] = nu * sinf(th);
            gm[c] = expf(gamma_log[c]);
        }
    }
}

// ------- bf16 MFMA GEMM (128x128 tile, BK=64, async staging, XOR swizzle) ---
// mode 1: GEMM1 split epilogue (N=4096), sector wave-uniform:
//   sector 0 -> bf16(gamma*val)->out_r; 1 -> out_i; 2,3 -> bf16 val -> out_o.
// mode 2: GEMM2 LN-folded epilogue; mu/rs computed inline from ssum/s2sum:
//   out[row][col] = rs*(acc - mu*s1[col]) + c2[col] + bias[col]
__global__ __launch_bounds__(256) void gemm_bf16(
    const ushort* __restrict__ A, const ushort* __restrict__ B,
    int K, int N, const float* __restrict__ bias, int mode,
    const float* __restrict__ gamma,
    ushort* __restrict__ out_r, ushort* __restrict__ out_i,
    ushort* __restrict__ out_o, float* __restrict__ outC,
    const float* __restrict__ ssum, const float* __restrict__ s2sum,
    const float* __restrict__ s1, const float* __restrict__ c2) {
    __shared__ ushort As[128 * 64];
    __shared__ ushort Bs[128 * 64];
    int tid = threadIdx.x;
    int lane = tid & 63, wave = tid >> 6;
    int wm = (wave & 1) * 64, wn = (wave >> 1) * 64;
    int lr = lane & 15, q = lane >> 4;
    long m0 = (long)blockIdx.y * 128;
    long n0 = (long)blockIdx.x * 128;
    floatx4 acc[4][4] = {};

    int rs_ = tid >> 3;
    int pg = ((tid & 7) ^ (rs_ & 7)) * 8;
    const ushort* Ap = A + (m0 + rs_) * (long)K + pg;
    const ushort* Bp = B + (n0 + rs_) * (long)K + pg;
    int swl = lr & 7;

    for (int kt = 0; kt < K; kt += 64) {
        __syncthreads();
#pragma unroll
        for (int j = 0; j < 4; ++j) {
            GLOAD_LDS16(Ap + kt + (long)(j * 32) * K, &As[(j * 256 + tid) * 8]);
            GLOAD_LDS16(Bp + kt + (long)(j * 32) * K, &Bs[(j * 256 + tid) * 8]);
        }
        __syncthreads();
#pragma unroll
        for (int s = 0; s < 2; ++s) {
            short8 af[4], bfv[4];
            int pq = ((s * 4 + q) ^ swl) * 8;
#pragma unroll
            for (int r = 0; r < 4; ++r)
                af[r] = *(const short8*)&As[(wm + r * 16 + lr) * 64 + pq];
#pragma unroll
            for (int c = 0; c < 4; ++c)
                bfv[c] = *(const short8*)&Bs[(wn + c * 16 + lr) * 64 + pq];
#pragma unroll
            for (int r = 0; r < 4; ++r)
#pragma unroll
                for (int c = 0; c < 4; ++c)
                    acc[r][c] = __builtin_amdgcn_mfma_f32_16x16x32_bf16(
                        af[r], bfv[c], acc[r][c], 0, 0, 0);
        }
    }

    if (mode == 2) {
        float muv[4][4], rsvv[4][4];
#pragma unroll
        for (int r = 0; r < 4; ++r)
#pragma unroll
            for (int g = 0; g < 4; ++g) {
                long row = m0 + wm + r * 16 + q * 4 + g;
                float sv = ssum[row], s2v = s2sum[row];
                float m = sv * (1.f / 2048.f);
                float var = s2v * (1.f / 2048.f) - m * m;
                muv[r][g] = m;
                rsvv[r][g] = rsqrtf(var + 1e-5f);
            }
#pragma unroll
        for (int r = 0; r < 4; ++r) {
#pragma unroll
            for (int c = 0; c < 4; ++c) {
                long col = n0 + wn + c * 16 + lr;
                float bc = c2[col] + bias[col];
                float s1c = s1[col];
#pragma unroll
                for (int g = 0; g < 4; ++g) {
                    long row = m0 + wm + r * 16 + q * 4 + g;
                    outC[row * (long)N + col] =
                        rsvv[r][g] * (acc[r][c][g] - muv[r][g] * s1c) + bc;
                }
            }
        }
    } else {
        int sector = (int)((n0 + wn) >> 10);          // wave-uniform
        int lc0 = (int)((n0 + wn) & 1023);
        if (sector < 2) {
            ushort* dst = sector ? out_i : out_r;
#pragma unroll
            for (int r = 0; r < 4; ++r) {
#pragma unroll
                for (int c = 0; c < 4; ++c) {
                    int lc = lc0 + c * 16 + lr;
                    float bv = bias[(sector << 10) + lc];
                    float gv = gamma[lc];
#pragma unroll
                    for (int g = 0; g < 4; ++g) {
                        long row = m0 + wm + r * 16 + q * 4 + g;
                        dst[row * 1024 + lc] = f2bf(gv * (acc[r][c][g] + bv));
                    }
                }
            }
        } else {
            int oc0 = (int)(n0 + wn - 2048);
#pragma unroll
            for (int r = 0; r < 4; ++r) {
#pragma unroll
                for (int c = 0; c < 4; ++c) {
                    int oc = oc0 + c * 16 + lr;
                    float bv = bias[2048 + oc];
#pragma unroll
                    for (int g = 0; g < 4; ++g) {
                        long row = m0 + wm + r * 16 + q * 4 + g;
                        out_o[row * 2048 + oc] = f2bf(acc[r][c][g] + bv);
                    }
                }
            }
        }
    }
}

// ---------------- chunked complex scan (bf16 planes, 2-ch/thread) -----------
// pass A: local scan per chunk (read-only), emit chunk-final state to
// carry planes laid out [b][ck][c] (float2-friendly).
__global__ __launch_bounds__(256) void scan_carries(
    const ushort* __restrict__ in_r, const ushort* __restrict__ in_i,
    float* __restrict__ carry_r, float* __restrict__ carry_i,
    const float* __restrict__ fr_, const float* __restrict__ fi_) {
    int t = blockIdx.x * 256 + threadIdx.x;   // BB*512*NCHUNK = 131072
    int ch2 = t & 511;
    int ck = (t >> 9) & (NCHUNK - 1);
    int b = t >> 15;
    int c = ch2 * 2;
    float fr0 = fr_[c], fi0 = fi_[c];
    float fr1 = fr_[c + 1], fi1 = fi_[c + 1];
    size_t base = ((size_t)(b * TT + ck * CHLEN)) * 1024 + c;
    float h0r = 0.f, h0i = 0.f, h1r = 0.f, h1i = 0.f;
#pragma unroll 4
    for (int j = 0; j < CHLEN; ++j) {
        size_t idx = base + (size_t)j * 1024;
        unsigned rr = *(const unsigned*)(in_r + idx);
        unsigned ii = *(const unsigned*)(in_i + idx);
        float r0 = bf2f((ushort)(rr & 0xffff)), r1 = bf2f((ushort)(rr >> 16));
        float i0 = bf2f((ushort)(ii & 0xffff)), i1 = bf2f((ushort)(ii >> 16));
        float n0r = fr0 * h0r - fi0 * h0i + r0;
        float n0i = fr0 * h0i + fi0 * h0r + i0;
        float n1r = fr1 * h1r - fi1 * h1i + r1;
        float n1i = fr1 * h1i + fi1 * h1r + i1;
        h0r = n0r; h0i = n0i; h1r = n1r; h1i = n1i;
    }
    size_t ci = ((size_t)(b * NCHUNK + ck)) * 1024 + c;
    *(float2*)&carry_r[ci] = make_float2(h0r, h1r);
    *(float2*)&carry_i[ci] = make_float2(h0i, h1i);
}

// pass B: recompute carry-in, rescan chunk, emit y' = h*silu(o) (bf16) and
// per-row sum/sumsq via wave-reduce + atomicAdd (for LN folded into GEMM2).
// grid: (NCHUNK, BB*2); block owns 512 channels x 32 rows.
__global__ __launch_bounds__(256) void scan_apply(
    const ushort* __restrict__ in_r, const ushort* __restrict__ in_i,
    const float* __restrict__ carry_r, const float* __restrict__ carry_i,
    const float* __restrict__ fr_, const float* __restrict__ fi_,
    const ushort* __restrict__ o, ushort* __restrict__ yb,
    float* __restrict__ ssum, float* __restrict__ s2sum) {
    int ck = blockIdx.x;
    int by = blockIdx.y;
    int b = by >> 1, half = by & 1;
    int tid = threadIdx.x;
    int ch2 = half * 256 + tid;
    int c = ch2 * 2;
    float fr0 = fr_[c], fi0 = fi_[c];
    float fr1 = fr_[c + 1], fi1 = fi_[c + 1];
    // f^CHLEN (CHLEN = 32 = 2^5)
    float a0r = fr0, a0i = fi0, a1r = fr1, a1i = fi1;
#pragma unroll
    for (int s = 0; s < 5; ++s) {
        float t0r = a0r * a0r - a0i * a0i, t0i = 2.f * a0r * a0i;
        float t1r = a1r * a1r - a1i * a1i, t1i = 2.f * a1r * a1i;
        a0r = t0r; a0i = t0i; a1r = t1r; a1i = t1i;
    }
    float H0r = 0.f, H0i = 0.f, H1r = 0.f, H1i = 0.f;
    size_t cb = ((size_t)(b * NCHUNK)) * 1024 + c;
    for (int k = 0; k < ck; ++k) {
        float2 crv = *(const float2*)&carry_r[cb + (size_t)k * 1024];
        float2 civ = *(const float2*)&carry_i[cb + (size_t)k * 1024];
        float n0r = a0r * H0r - a0i * H0i + crv.x;
        float n0i = a0r * H0i + a0i * H0r + civ.x;
        float n1r = a1r * H1r - a1i * H1i + crv.y;
        float n1i = a1r * H1i + a1i * H1r + civ.y;
        H0r = n0r; H0i = n0i; H1r = n1r; H1i = n1i;
    }
    size_t rowbase = (size_t)(b * TT + ck * CHLEN);
    float h0r = H0r, h0i = H0i, h1r = H1r, h1i = H1i;
#pragma unroll 2
    for (int j = 0; j < CHLEN; ++j) {
        size_t row = rowbase + j;
        size_t idx = row * 1024 + c;
        unsigned rr = *(const unsigned*)(in_r + idx);
        unsigned ii = *(const unsigned*)(in_i + idx);
        unsigned oo1 = *(const unsigned*)(o + row * 2048 + c);
        unsigned oo2 = *(const unsigned*)(o + row * 2048 + c + 1024);
        float r0 = bf2f((ushort)(rr & 0xffff)), r1 = bf2f((ushort)(rr >> 16));
        float i0 = bf2f((ushort)(ii & 0xffff)), i1 = bf2f((ushort)(ii >> 16));
        float n0r = fr0 * h0r - fi0 * h0i + r0;
        float n0i = fr0 * h0i + fi0 * h0r + i0;
        float n1r = fr1 * h1r - fi1 * h1i + r1;
        float n1i = fr1 * h1i + fi1 * h1r + i1;
        h0r = n0r; h0i = n0i; h1r = n1r; h1i = n1i;
        float o0 = bf2f((ushort)(oo1 & 0xffff)), o1 = bf2f((ushort)(oo1 >> 16));
        float o2 = bf2f((ushort)(oo2 & 0xffff)), o3 = bf2f((ushort)(oo2 >> 16));
        float y0 = h0r * silu(o0), y1 = h1r * silu(o1);
        float y2 = h0i * silu(o2), y3 = h1i * silu(o3);
        *(unsigned*)(yb + row * 2048 + c) =
            (unsigned)f2bf(y0) | ((unsigned)f2bf(y1) << 16);
        *(unsigned*)(yb + row * 2048 + c + 1024) =
            (unsigned)f2bf(y2) | ((unsigned)f2bf(y3) << 16);
        float s = y0 + y1 + y2 + y3;
        float s2 = y0 * y0 + y1 * y1 + y2 * y2 + y3 * y3;
#pragma unroll
        for (int off = 32; off > 0; off >>= 1) {
            s += __shfl_down(s, off, 64);
            s2 += __shfl_down(s2, off, 64);
        }
        if ((tid & 63) == 0) {
            atomicAdd(&ssum[row], s);
            atomicAdd(&s2sum[row], s2);
        }
    }
}

// ---------------- launch ----------------

extern "C" void kernel_launch(void* const* d_in, const int* in_sizes, int n_in,
                              void* d_out, int out_size, void* d_ws, size_t ws_size,
                              hipStream_t stream) {
    const float* x         = (const float*)d_in[0];
    const float* W_in      = (const float*)d_in[1];
    const float* b_in      = (const float*)d_in[2];
    const float* nu_log    = (const float*)d_in[3];
    const float* theta_log = (const float*)d_in[4];
    const float* gamma_log = (const float*)d_in[5];
    const float* ln_w      = (const float*)d_in[6];
    const float* ln_b      = (const float*)d_in[7];
    const float* W_out     = (const float*)d_in[8];
    const float* b_out     = (const float*)d_in[9];
    float* out = (float*)d_out;

    char* ws = (char*)d_ws;
    size_t off = 0;
    auto alloc = [&](size_t bytes) {
        char* p = ws + off;
        off += (bytes + 255) & ~(size_t)255;
        return p;
    };
    ushort* xb    = (ushort*)alloc((size_t)ROWS * 1024 * 2);
    ushort* WinT  = (ushort*)alloc((size_t)4096 * 1024 * 2);
    ushort* W1T   = (ushort*)alloc((size_t)1024 * 2048 * 2);
    float*  fr    = (float*)alloc(1024 * 4);
    float*  fi    = (float*)alloc(1024 * 4);
    float*  gm    = (float*)alloc(1024 * 4);
    float*  zbuf  = (float*)alloc((size_t)(2048 + 2 * ROWS) * 4); // s1|c2|ssum|s2sum
    float*  s1    = zbuf;
    float*  c2    = zbuf + 1024;
    float*  ssum  = zbuf + 2048;
    float*  s2sum = zbuf + 2048 + ROWS;
    ushort* in_r  = (ushort*)alloc((size_t)ROWS * 1024 * 2);
    ushort* in_i  = (ushort*)alloc((size_t)ROWS * 1024 * 2);
    ushort* obuf  = (ushort*)alloc((size_t)ROWS * 2048 * 2);
    float*  car_r = (float*)alloc((size_t)BB * NCHUNK * 1024 * 4);
    float*  car_i = (float*)alloc((size_t)BB * NCHUNK * 1024 * 4);
    ushort* yb    = (ushort*)alloc((size_t)ROWS * 2048 * 2);

    hipMemsetAsync(zbuf, 0, (size_t)(2048 + 2 * ROWS) * 4, stream);

    prep_all<<<PREP_A + PREP_B + PREP_C + 4, 256, 0, stream>>>(
        x, xb, W_in, WinT, W_out, W1T, ln_w, ln_b, s1, c2,
        nu_log, theta_log, gamma_log, fr, fi, gm);

    gemm_bf16<<<dim3(4096 / 128, ROWS / 128), 256, 0, stream>>>(
        xb, WinT, 1024, 4096, b_in, 1, gm, in_r, in_i, obuf, nullptr,
        nullptr, nullptr, nullptr, nullptr);

    scan_carries<<<BB * 512 * NCHUNK / 256, 256, 0, stream>>>(
        in_r, in_i, car_r, car_i, fr, fi);
    scan_apply<<<dim3(NCHUNK, BB * 2), 256, 0, stream>>>(
        in_r, in_i, car_r, car_i, fr, fi, obuf, yb, ssum, s2sum);

    gemm_bf16<<<dim3(1024 / 128, ROWS / 128), 256, 0, stream>>>(
        yb, W1T, 2048, 1024, b_out, 2, nullptr, nullptr, nullptr, nullptr, out,
        ssum, s2sum, s1, c2);
}